// Round 3
// baseline (932.014 us; speedup 1.0000x reference)
//
#include <hip/hip_runtime.h>

typedef __attribute__((ext_vector_type(8))) __bf16   bf16x8;
typedef __attribute__((ext_vector_type(4))) __bf16   bf16x4;
typedef __attribute__((ext_vector_type(8))) _Float16 halfx8;
typedef __attribute__((ext_vector_type(4))) float    floatx4;

#define S_  1024
#define D_  1024
#define H_  16
#define DK_ 64
#define B_  4
#define M_  4096  // B*S

// ---------------- fp32 -> bf16 ingest of query/key/value ----------------
__global__ __launch_bounds__(256) void cvt_bf16(
    const float* __restrict__ q, const float* __restrict__ k,
    const float* __restrict__ v, __bf16* __restrict__ X)
{
  const int z = blockIdx.y;
  const float* src = (z == 0) ? q : (z == 1) ? k : v;
  __bf16* dst = X + (size_t)z * 4194304;
  const size_t idx = ((size_t)blockIdx.x * 256 + threadIdx.x) * 8;
  floatx4 a = *(const floatx4*)(src + idx);
  floatx4 b = *(const floatx4*)(src + idx + 4);
  bf16x8 o;
#pragma unroll
  for (int j = 0; j < 4; ++j) { o[j] = (__bf16)a[j]; o[4 + j] = (__bf16)b[j]; }
  *(bf16x8*)(dst + idx) = o;
}

// ---------------- mask dtype probe: int32 0/1 has zero high bytes ----------------
__global__ __launch_bounds__(256) void mask_probe(const unsigned char* __restrict__ m,
                                                  int* __restrict__ flag)
{
  __shared__ unsigned sacc[256];
  const int t = threadIdx.x;
  unsigned acc = 0;
  for (int i = t; i < 4096; i += 256)
    if (i & 3) acc |= m[i];
  sacc[t] = acc;
  __syncthreads();
  if (t == 0) {
    unsigned tot = 0;
    for (int i = 0; i < 256; ++i) tot |= sacc[i];
    flag[0] = tot ? 1 : 0;  // 1 => bytes (bool), 0 => int32
  }
}

// ---------------- weight transpose: WT[n*D + k] = (bf16)W[k*D + n] ----------------
__global__ __launch_bounds__(256) void transpose_w(
    const float* __restrict__ W0, const float* __restrict__ W1,
    const float* __restrict__ W2, const float* __restrict__ W3,
    __bf16* __restrict__ WT)
{
  const float* W = (blockIdx.z == 0) ? W0 : (blockIdx.z == 1) ? W1
                 : (blockIdx.z == 2) ? W2 : W3;
  __bf16* O = WT + (size_t)blockIdx.z * (D_ * (size_t)D_);
  __shared__ __bf16 T[64 * 72];
  const int t = threadIdx.x;
  const int r0 = blockIdx.y * 64, c0 = blockIdx.x * 64;
#pragma unroll
  for (int it = 0; it < 4; ++it) {
    int idx = t * 4 + it * 1024;
    int r = idx >> 6, c = idx & 63;  // c multiple of 4
    floatx4 a = *(const floatx4*)(W + (size_t)(r0 + r) * D_ + c0 + c);
    bf16x4 o;
#pragma unroll
    for (int j = 0; j < 4; ++j) o[j] = (__bf16)a[j];
    *(bf16x4*)(&T[r * 72 + c]) = o;
  }
  __syncthreads();
#pragma unroll
  for (int it = 0; it < 2; ++it) {
    int idx = t * 8 + it * 2048;
    int orow = idx >> 6, oc = idx & 63;  // oc multiple of 8
    bf16x8 v;
#pragma unroll
    for (int j = 0; j < 8; ++j) v[j] = T[(oc + j) * 72 + orow];
    *(bf16x8*)(O + (size_t)(c0 + orow) * D_ + (r0 + oc)) = v;
  }
}

// ---------------- 128x128-tile GEMM: C = X[M,1024] @ W + bias ----------------
// X is bf16, WT is bf16 B^T layout [N][K], bias fp32. modes:
//   0: fp32 out[m*1024+n]                     (out projection)
//   1: fp16 Q[b,h,s,dk] = v*0.125             (score scale folded in)
//   2: fp16 K[b,h,s,dk]
//   3: bf16 Vt[b,h,dk,s]                      (transposed via LDS epilogue)
__global__ __launch_bounds__(256) void gemm128(
    const __bf16* __restrict__ X, const __bf16* __restrict__ WT,
    const float* __restrict__ bias, void* __restrict__ outp, const int mode)
{
  __shared__ __bf16 sh[2 * 128 * 72];
  __bf16* As = sh;
  __bf16* Bs = sh + 128 * 72;
  const int t = threadIdx.x;
  const int w = t >> 6, lane = t & 63, quad = lane >> 4, cl = lane & 15;
  const int wm = w >> 1, wn = w & 1;
  const int m0 = blockIdx.x * 128, n0 = blockIdx.y * 128;

  floatx4 acc[4][4];
#pragma unroll
  for (int i = 0; i < 4; ++i)
#pragma unroll
    for (int j = 0; j < 4; ++j) acc[i][j] = (floatx4){0.f, 0.f, 0.f, 0.f};

  for (int kt = 0; kt < 16; ++kt) {
    const int k0 = kt * 64;
    __syncthreads();
#pragma unroll
    for (int it = 0; it < 4; ++it) {
      int idx = t * 8 + it * 2048;
      int r = idx >> 6, c = idx & 63;
      *(bf16x8*)(&As[r * 72 + c]) = *(const bf16x8*)(X  + (size_t)(m0 + r) * D_ + k0 + c);
      *(bf16x8*)(&Bs[r * 72 + c]) = *(const bf16x8*)(WT + (size_t)(n0 + r) * D_ + k0 + c);
    }
    __syncthreads();
#pragma unroll
    for (int ks = 0; ks < 2; ++ks) {
      bf16x8 a[4], b[4];
#pragma unroll
      for (int mt = 0; mt < 4; ++mt)
        a[mt] = *(const bf16x8*)(&As[(wm * 64 + mt * 16 + cl) * 72 + ks * 32 + quad * 8]);
#pragma unroll
      for (int nt = 0; nt < 4; ++nt)
        b[nt] = *(const bf16x8*)(&Bs[(wn * 64 + nt * 16 + cl) * 72 + ks * 32 + quad * 8]);
#pragma unroll
      for (int mt = 0; mt < 4; ++mt)
#pragma unroll
        for (int nt = 0; nt < 4; ++nt)
          acc[mt][nt] = __builtin_amdgcn_mfma_f32_16x16x32_bf16(a[mt], b[nt], acc[mt][nt], 0, 0, 0);
    }
  }

  if (mode <= 2) {
#pragma unroll
    for (int mt = 0; mt < 4; ++mt)
#pragma unroll
      for (int nt = 0; nt < 4; ++nt) {
        const int nl = n0 + wn * 64 + nt * 16 + cl;
        const float bv = bias[nl];
#pragma unroll
        for (int r = 0; r < 4; ++r) {
          const int ml = m0 + wm * 64 + mt * 16 + quad * 4 + r;
          float v = acc[mt][nt][r] + bv;
          if (mode == 0) {
            ((float*)outp)[(size_t)ml * D_ + nl] = v;
          } else {
            if (mode == 1) v *= 0.125f;
            const int bb = ml >> 10, ss = ml & 1023, hh = nl >> 6, dd = nl & 63;
            ((_Float16*)outp)[(size_t)((bb * H_ + hh) * S_ + ss) * DK_ + dd] = (_Float16)v;
          }
        }
      }
  } else {
    // V: transpose the wave's 64x64 quadrant via LDS, write coalesced rows of Vt
    __syncthreads();  // all waves done reading As/Bs
    __bf16* T = sh + w * (64 * 72);
    const int hbase = n0 + wn * 64;  // 64-aligned -> single head
#pragma unroll
    for (int mt = 0; mt < 4; ++mt)
#pragma unroll
      for (int nt = 0; nt < 4; ++nt) {
        const int nl = hbase + nt * 16 + cl;
        const float bv = bias[nl];
        const int dk = nt * 16 + cl;
#pragma unroll
        for (int r = 0; r < 4; ++r) {
          const int sl = mt * 16 + quad * 4 + r;
          T[dk * 72 + sl] = (__bf16)(acc[mt][nt][r] + bv);
        }
      }
    __syncthreads();
    const int bb = m0 >> 10;
    const int hh = hbase >> 6;
    __bf16* out = (__bf16*)outp;
#pragma unroll
    for (int i = 0; i < 8; ++i) {
      int idx = lane * 8 + i * 512;
      int dk = idx >> 6, sl = idx & 63;  // sl multiple of 8
      bf16x8 v = *(const bf16x8*)(&T[dk * 72 + sl]);
      int sg = (m0 & 1023) + wm * 64 + sl;
      *(bf16x8*)(out + (size_t)((bb * H_ + hh) * DK_ + dk) * S_ + sg) = v;
    }
  }
}

// ---------------- attention: scores -> exp -> p' out (fp32) + l + O=P@V ----------------
// one wg (4 waves) per (bh, 64-row q-tile); wave w owns rows [w*16, w*16+16)
__global__ __launch_bounds__(256) void attn_kernel(
    const _Float16* __restrict__ Q, const _Float16* __restrict__ K,
    const __bf16* __restrict__ Vt, const unsigned char* __restrict__ maskB,
    const int* __restrict__ mflag,
    float* __restrict__ attnW, __bf16* __restrict__ AO, float* __restrict__ lout)
{
  __shared__ _Float16 Qs[64 * 72];
  __shared__ _Float16 Ks[128 * 72];
  __shared__ __bf16   Vts[64 * 136];
  __shared__ __bf16   Ps[4 * 16 * 136];

  const int t = threadIdx.x;
  const int w = t >> 6, lane = t & 63, quad = lane >> 4, cl = lane & 15;
  const int bh = blockIdx.y;        // b*16+h
  const int q0 = blockIdx.x * 64;
  const bool mbyte = (*mflag != 0);
  const int* maskI = (const int*)maskB;

  { // stage Q tile (contiguous 64x64 fp16)
    const _Float16* g = Q + (size_t)(bh * S_ + q0) * DK_;
#pragma unroll
    for (int it = 0; it < 2; ++it) {
      int idx = t * 8 + it * 2048;
      *(halfx8*)(&Qs[(idx >> 6) * 72 + (idx & 63)]) = *(const halfx8*)(g + idx);
    }
  }

  floatx4 acc_o[4];
#pragma unroll
  for (int i = 0; i < 4; ++i) acc_o[i] = (floatx4){0.f, 0.f, 0.f, 0.f};
  float lacc[4] = {0.f, 0.f, 0.f, 0.f};

  __bf16* Psw = Ps + w * (16 * 136);
  const long maskbase = (long)bh * S_ * S_;

  for (int kt = 0; kt < 8; ++kt) {
    const int k0 = kt * 128;
    __syncthreads();  // prior PV reads done before restaging
    { // stage K tile (contiguous 128x64 fp16)
      const _Float16* g = K + (size_t)(bh * S_ + k0) * DK_;
#pragma unroll
      for (int it = 0; it < 4; ++it) {
        int idx = t * 8 + it * 2048;
        *(halfx8*)(&Ks[(idx >> 6) * 72 + (idx & 63)]) = *(const halfx8*)(g + idx);
      }
    }
    { // stage Vt tile: rows dk, cols s (256B rows)
      const __bf16* g = Vt + (size_t)bh * DK_ * S_ + k0;
#pragma unroll
      for (int it = 0; it < 4; ++it) {
        int idx = t * 8 + it * 2048;
        int r = idx >> 7, c = idx & 127;
        *(bf16x8*)(&Vts[r * 136 + c]) = *(const bf16x8*)(g + (size_t)r * S_ + c);
      }
    }
    __syncthreads();

    // scores: [16 q] x [128 k], f16 MFMA; then mask+exp -> Ps (bf16) + l
    halfx8 a0 = *(const halfx8*)(&Qs[(w * 16 + cl) * 72 + quad * 8]);
    halfx8 a1 = *(const halfx8*)(&Qs[(w * 16 + cl) * 72 + 32 + quad * 8]);
#pragma unroll
    for (int nt = 0; nt < 8; ++nt) {
      floatx4 s = (floatx4){0.f, 0.f, 0.f, 0.f};
      halfx8 b0 = *(const halfx8*)(&Ks[(nt * 16 + cl) * 72 + quad * 8]);
      halfx8 b1 = *(const halfx8*)(&Ks[(nt * 16 + cl) * 72 + 32 + quad * 8]);
      s = __builtin_amdgcn_mfma_f32_16x16x32_f16(a0, b0, s, 0, 0, 0);
      s = __builtin_amdgcn_mfma_f32_16x16x32_f16(a1, b1, s, 0, 0, 0);
#pragma unroll
      for (int r = 0; r < 4; ++r) {
        const int rowl = w * 16 + quad * 4 + r;
        const long off = maskbase + (long)(q0 + rowl) * S_ + (k0 + nt * 16 + cl);
        int mk;
        if (mbyte) mk = maskB[off]; else mk = maskI[off];
        float sv = s[r];
        sv = (sv < 25.f) ? sv : 25.f;          // safety clamp, keeps everything finite
        float p = mk ? 0.0f : __expf(sv);
        __bf16 pb = (__bf16)p;
        lacc[r] += (float)pb;  // l from the rounded value -> stored weights sum to 1
        Psw[(quad * 4 + r) * 136 + nt * 16 + cl] = pb;
      }
    }
    __syncthreads();  // not strictly needed (per-wave Ps), kept for safety

    { // coalesced fp32 write of unnormalized p' tile to attn output region
      float* g = attnW + (long)(bh * S_ + q0 + w * 16) * S_ + k0;
#pragma unroll
      for (int i = 0; i < 4; ++i) {
        int idx = lane * 8 + i * 512;
        int r = idx >> 7, c = idx & 127;
        bf16x8 v = *(const bf16x8*)(&Psw[r * 136 + c]);
        floatx4 lo, hi;
#pragma unroll
        for (int j = 0; j < 4; ++j) { lo[j] = (float)v[j]; hi[j] = (float)v[4 + j]; }
        *(floatx4*)(g + (long)r * S_ + c) = lo;
        *(floatx4*)(g + (long)r * S_ + c + 4) = hi;
      }
    }

    // PV: O[16 q][64 dk] += P[16][128] @ V[128][64]
#pragma unroll
    for (int ks = 0; ks < 4; ++ks) {
      bf16x8 a = *(const bf16x8*)(&Psw[cl * 136 + ks * 32 + quad * 8]);
#pragma unroll
      for (int nt2 = 0; nt2 < 4; ++nt2) {
        bf16x8 b = *(const bf16x8*)(&Vts[(nt2 * 16 + cl) * 136 + ks * 32 + quad * 8]);
        acc_o[nt2] = __builtin_amdgcn_mfma_f32_16x16x32_bf16(a, b, acc_o[nt2], 0, 0, 0);
      }
    }
  }

  // reduce row sums across the 16 col-lanes (butterfly within the 16-lane group)
#pragma unroll
  for (int r = 0; r < 4; ++r) {
    float v = lacc[r];
    v += __shfl_xor(v, 1); v += __shfl_xor(v, 2);
    v += __shfl_xor(v, 4); v += __shfl_xor(v, 8);
    lacc[r] = v;
  }
  const int bb = bh >> 4, hh = bh & 15;
#pragma unroll
  for (int r = 0; r < 4; ++r) {
    const int rowg = q0 + w * 16 + quad * 4 + r;
    if (cl == 0) lout[bh * S_ + rowg] = lacc[r];
    const float rl = (lacc[r] > 0.f) ? 1.0f / lacc[r] : 0.f;  // guard fully-masked row
#pragma unroll
    for (int nt2 = 0; nt2 < 4; ++nt2) {
      float v = acc_o[nt2][r] * rl;
      AO[(size_t)(bb * S_ + rowg) * D_ + hh * DK_ + nt2 * 16 + cl] = (__bf16)v;
    }
  }
}

// ---------------- normalize attn weights in place (fp32) ----------------
__global__ __launch_bounds__(256) void norm_attn(float* __restrict__ attnW,
                                                 const float* __restrict__ l)
{
  const int row = blockIdx.x;
  const float lv = l[row];
  const float rl = (lv > 0.f) ? 1.0f / lv : 0.f;  // guard fully-masked row
  const size_t base = (size_t)row * S_ + threadIdx.x * 4;
  floatx4 v = *(const floatx4*)(attnW + base);
#pragma unroll
  for (int j = 0; j < 4; ++j) v[j] *= rl;
  *(floatx4*)(attnW + base) = v;
}

extern "C" void kernel_launch(void* const* d_in, const int* in_sizes, int n_in,
                              void* d_out, int out_size, void* d_ws, size_t ws_size,
                              hipStream_t stream)
{
  (void)in_sizes; (void)n_in; (void)out_size; (void)ws_size;
  const float* query = (const float*)d_in[0];
  const float* key   = (const float*)d_in[1];
  const float* value = (const float*)d_in[2];
  const unsigned char* mask = (const unsigned char*)d_in[3];
  const float* Wq = (const float*)d_in[4];
  const float* bq = (const float*)d_in[5];
  const float* Wk = (const float*)d_in[6];
  const float* bk = (const float*)d_in[7];
  const float* Wv = (const float*)d_in[8];
  const float* bv = (const float*)d_in[9];
  const float* Wo = (const float*)d_in[10];
  const float* bo = (const float*)d_in[11];

  __bf16* ws = (__bf16*)d_ws;                       // element offsets in bf16 units
  __bf16*   wt   = ws;                               // 4 x 1M bf16   ( 8 MB)
  _Float16* Qws  = (_Float16*)(ws + 4  * 1048576);   // fp16 [B,H,S,DK]
  _Float16* Kws  = (_Float16*)(ws + 8  * 1048576);   // fp16 [B,H,S,DK]
  __bf16*   Vtws = ws + 12 * 1048576;                // bf16 [B,H,DK,S]
  __bf16*   AOws = ws + 16 * 1048576;                // bf16 [B,S,D]
  __bf16*   Xbf  = ws + 20 * 1048576;                // bf16 q,k,v    (3 x 8 MB)
  float*    lws  = (float*)(ws + 32 * 1048576);      // fp32 [B*H*S]  (256 KB)
  int*      mfl  = (int*)(ws + 32 * 1048576 + 131072);

  float* outO  = (float*)d_out;                      // [B,S,D]   4M fp32
  float* attnW = outO + 4 * 1048576;                 // [B,H,S,S] 64M fp32

  cvt_bf16<<<dim3(2048, 3), 256, 0, stream>>>(query, key, value, Xbf);
  mask_probe<<<1, 256, 0, stream>>>(mask, mfl);
  transpose_w<<<dim3(16, 16, 4), 256, 0, stream>>>(Wq, Wk, Wv, Wo, wt);
  gemm128<<<dim3(32, 8), 256, 0, stream>>>(Xbf,               wt,               bq, (void*)Qws,  1);
  gemm128<<<dim3(32, 8), 256, 0, stream>>>(Xbf + 4194304,     wt + 1048576,     bk, (void*)Kws,  2);
  gemm128<<<dim3(32, 8), 256, 0, stream>>>(Xbf + 2 * 4194304, wt + 2 * 1048576, bv, (void*)Vtws, 3);
  attn_kernel<<<dim3(16, 64), 256, 0, stream>>>(Qws, Kws, Vtws, mask, mfl, attnW, AOws, lws);
  norm_attn<<<B_ * H_ * S_, 256, 0, stream>>>(attnW, lws);
  gemm128<<<dim3(32, 8), 256, 0, stream>>>(AOws, wt + 3 * 1048576, bo, (void*)outO, 0);
}